// Round 8
// baseline (123.900 us; speedup 1.0000x reference)
//
#include <hip/hip_runtime.h>

#define DEVFN static __device__ __forceinline__

constexpr int kLtot = 1024, kC = 32, kB = 2;
constexpr int kNCH = kB * kC;          // 64 chains

// phase1 per-wave LDS: two 2048B A-slots (ring) + 17x144B pbuf (P bounce rows 0-15, v row 16)
constexpr int kSlotB = 2048;
constexpr int kPbufB = 17 * 144;       // 2448
constexpr int kWaveB = 2 * kSlotB + kPbufB;  // 6544 (16B aligned)

typedef int v2i __attribute__((ext_vector_type(2)));

DEVFN void gload16(const void* g, void* l) {
  __builtin_amdgcn_global_load_lds((const __attribute__((address_space(1))) void*)g,
                                   (__attribute__((address_space(3))) void*)l, 16, 0, 0);
}

// xor-16 via ds_swizzle (DS pipe — overlaps VALU; R3/R6-proven faster than permlane16_swap)
DEVFN float redpair16(float x) {
  return x + __int_as_float(__builtin_amdgcn_ds_swizzle(__float_as_int(x), 0x401F));
}
DEVFN float redpair32(float x) {
#if __has_builtin(__builtin_amdgcn_permlane32_swap)
  v2i r = __builtin_amdgcn_permlane32_swap(__float_as_int(x), __float_as_int(x), false, false);
  return __int_as_float(r.x) + __int_as_float(r.y);
#else
  return x + __shfl_xor(x, 32);
#endif
}
DEVFN float redq(float x) { return redpair32(redpair16(x)); }  // sum over the 4 kq-partners

DEVFN float sel4(float x0, float x1, float x2, float x3, int b) {
  float lo = (b & 1) ? x1 : x0;
  float hi = (b & 1) ? x3 : x2;
  return (b & 2) ? hi : lo;
}

// ---------------- Phase 1: chunk transition P_g + response v_g ----------------
// 1 chunk per wave, 4 waves per block. Lane (kq, ka, kc): partials np[ka+4r][4kc+jj] over
// k in [4kq,4kq+4); reduce over kq via ds_swizzle(xor16) + permlane32; p redistributed via
// per-wave LDS transpose bounce. P starts as A_0 (step 0 free). G = chunks/chain (template).
template <int G>
__global__ __launch_bounds__(256, 4) void pscan_phase1(
    const float* __restrict__ Ar, const float* __restrict__ Ai,
    const float* __restrict__ Xr, const float* __restrict__ Xi,
    float* __restrict__ Pg, float* __restrict__ Vg) {
  constexpr int CL = kLtot / G;
  __shared__ __align__(16) float ldsF[4 * (kWaveB / 4)];
  const int lane = threadIdx.x & 63;
  const int wid = threadIdx.x >> 6;
  const int kq = lane >> 4, ka = (lane >> 2) & 3, kc = lane & 3;
  const int jv = 4 * kc + ka;

  const int ck = blockIdx.x * 4 + wid;
  const int chain = ck / G, g = ck % G;
  const int bb = chain >> 5, cc = chain & 31;
  const int t0 = g * CL;

  char* ldsW = (char*)ldsF + wid * kWaveB;
  char* pbase = ldsW + 2 * kSlotB;
  const int laneA = ka * 64 + kq * 16;
  const int laneAv = laneA + kc * 256;

  const size_t aBase = ((size_t)(bb * kLtot + t0) * kC + cc) * 256;
  const size_t xBase2 = ((size_t)(bb * kLtot + t0) * kC + cc) * 16;
  const float* arPtr = Ar + aBase + (size_t)lane * 4;
  const float* aiPtr = Ai + aBase + (size_t)lane * 4;
  const float* xrPtr = Xr + xBase2 + jv;
  const float* xiPtr = Xi + xBase2 + jv;

  char* wA = pbase + (ka + 4 * kq) * 144 + kc * 32;           // bounce write row ka+4kq, quad kc
  const char* rA = pbase + (4 * kq) * 144 + kc * 32;          // bounce read rows 4kq+kk
  char* vwA = pbase + 2304 + jv * 8;                          // v write (kq==0 lanes only)
  const char* vrA = pbase + 2304 + kq * 32;                   // v read slice

  float xrP[2], xiP[2];
  auto issueStep = [&](int t) {                               // 4 vmem ops, always
    const size_t ao = (size_t)t * (kC * 256);
    char* sd = ldsW + (t & 1) * kSlotB;
    gload16(arPtr + ao, sd);
    gload16(aiPtr + ao, sd + 1024);
    xrP[t & 1] = xrPtr[(size_t)t * (kC * 16)];
    xiP[t & 1] = xiPtr[(size_t)t * (kC * 16)];
  };

  issueStep(0);
  asm volatile("" ::: "memory");
  issueStep(1);
  asm volatile("" ::: "memory");

  float prk[4][4], pik[4][4];   // p[kk][jj] = P[4kq+kk][4kc+jj]
  float npr[4][4], npi[4][4];   // np[r][jj] = P_new[ka+4r][4kc+jj]
  float vre[4], vim[4];         // v[4kq+kk]
  float vnr = 0.f, vni = 0.f;

  // ---- init: P = A_0, v = x_0 (skips the identity matmul) ----
  asm volatile("s_waitcnt vmcnt(4)" ::: "memory");  // slot 0 resident
  {
    const char* sb = ldsW;
#pragma unroll
    for (int kk = 0; kk < 4; ++kk) {
      const float4 a4 = *(const float4*)(sb + (4 * kq + kk) * 64 + kc * 16);
      const float4 b4 = *(const float4*)(sb + 1024 + (4 * kq + kk) * 64 + kc * 16);
      prk[kk][0] = a4.x; prk[kk][1] = a4.y; prk[kk][2] = a4.z; prk[kk][3] = a4.w;
      pik[kk][0] = b4.x; pik[kk][1] = b4.y; pik[kk][2] = b4.z; pik[kk][3] = b4.w;
    }
    const float* xr0 = Xr + xBase2;
    const float* xi0 = Xi + xBase2;
#pragma unroll
    for (int kk = 0; kk < 4; ++kk) {
      vre[kk] = xr0[4 * kq + kk];
      vim[kk] = xi0[4 * kq + kk];
    }
  }
  asm volatile("s_waitcnt lgkmcnt(0)" ::: "memory");  // slot-0 reads done before re-staging
  issueStep(2);
  asm volatile("" ::: "memory");

  auto stepCompute = [&](int t) {
    const char* sb = ldsW + (t & 1) * kSlotB;
    const char* sbl = sb + laneA;
#pragma unroll
    for (int r = 0; r < 4; ++r) {
      const float4 a4 = *(const float4*)(sbl + r * 256);
      const float4 b4 = *(const float4*)(sbl + 1024 + r * 256);
#pragma unroll
      for (int jj = 0; jj < 4; ++jj) {
        float nr = a4.x * prk[0][jj] - b4.x * pik[0][jj];
        float ni = a4.x * pik[0][jj] + b4.x * prk[0][jj];
        nr += a4.y * prk[1][jj] - b4.y * pik[1][jj];
        ni += a4.y * pik[1][jj] + b4.y * prk[1][jj];
        nr += a4.z * prk[2][jj] - b4.z * pik[2][jj];
        ni += a4.z * pik[2][jj] + b4.z * prk[2][jj];
        nr += a4.w * prk[3][jj] - b4.w * pik[3][jj];
        ni += a4.w * pik[3][jj] + b4.w * prk[3][jj];
        npr[r][jj] = nr; npi[r][jj] = ni;
      }
    }
    {
      const float4 a4 = *(const float4*)(sb + laneAv);
      const float4 b4 = *(const float4*)(sb + laneAv + 1024);
      float pr = a4.x * vre[0] - b4.x * vim[0];
      float pi = a4.x * vim[0] + b4.x * vre[0];
      pr += a4.y * vre[1] - b4.y * vim[1];  pi += a4.y * vim[1] + b4.y * vre[1];
      pr += a4.z * vre[2] - b4.z * vim[2];  pi += a4.z * vim[2] + b4.z * vre[2];
      pr += a4.w * vre[3] - b4.w * vim[3];  pi += a4.w * vim[3] + b4.w * vre[3];
      pr = redq(pr); pi = redq(pi);
      vnr = pr + xrP[t & 1];
      vni = pi + xiP[t & 1];
    }
#pragma unroll
    for (int r = 0; r < 4; ++r)
#pragma unroll
      for (int jj = 0; jj < 4; ++jj) {
        npr[r][jj] = redq(npr[r][jj]);
        npi[r][jj] = redq(npi[r][jj]);
      }
  };

  auto stepBounce = [&]() {
#pragma unroll
    for (int u = 0; u < 2; ++u) {
      float4 w;
      w.x = sel4(npr[0][2 * u], npr[1][2 * u], npr[2][2 * u], npr[3][2 * u], kq);
      w.y = sel4(npi[0][2 * u], npi[1][2 * u], npi[2][2 * u], npi[3][2 * u], kq);
      w.z = sel4(npr[0][2 * u + 1], npr[1][2 * u + 1], npr[2][2 * u + 1], npr[3][2 * u + 1], kq);
      w.w = sel4(npi[0][2 * u + 1], npi[1][2 * u + 1], npi[2][2 * u + 1], npi[3][2 * u + 1], kq);
      *(float4*)(wA + u * 16) = w;
    }
    if (kq == 0) *(float2*)vwA = make_float2(vnr, vni);
    // no explicit lgkmcnt(0): same-wave DS ops are in-order; compiler inserts precise waits.
#pragma unroll
    for (int kk = 0; kk < 4; ++kk) {
      const float4 q0 = *(const float4*)(rA + kk * 144);
      const float4 q1 = *(const float4*)(rA + kk * 144 + 16);
      prk[kk][0] = q0.x; pik[kk][0] = q0.y; prk[kk][1] = q0.z; pik[kk][1] = q0.w;
      prk[kk][2] = q1.x; pik[kk][2] = q1.y; prk[kk][3] = q1.z; pik[kk][3] = q1.w;
    }
    const float4 v0 = *(const float4*)(vrA);
    const float4 v1 = *(const float4*)(vrA + 16);
    vre[0] = v0.x; vim[0] = v0.y; vre[1] = v0.z; vim[1] = v0.w;
    vre[2] = v1.x; vim[2] = v1.y; vre[3] = v1.z; vim[3] = v1.w;
  };

#pragma unroll 2
  for (int t = 1; t < CL - 2; ++t) {
    asm volatile("s_waitcnt vmcnt(4)" ::: "memory");
    stepCompute(t);
    stepBounce();
    issueStep(t + 2);
  }
  asm volatile("s_waitcnt vmcnt(4)" ::: "memory");
  stepCompute(CL - 2);
  stepBounce();
  asm volatile("s_waitcnt vmcnt(0)" ::: "memory");
  stepCompute(CL - 1);

  // store P_g (row-major [i][k] float2) and v_g from the kq==0 lanes
  if (kq == 0) {
    float* pd = Pg + (size_t)ck * 512;
#pragma unroll
    for (int r = 0; r < 4; ++r) {
#pragma unroll
      for (int u = 0; u < 2; ++u) {
        float4 o;
        o.x = npr[r][2 * u];     o.y = npi[r][2 * u];
        o.z = npr[r][2 * u + 1]; o.w = npi[r][2 * u + 1];
        *(float4*)(pd + (ka + 4 * r) * 32 + 8 * kc + 4 * u) = o;
      }
    }
    *(float2*)(Vg + (size_t)ck * 32 + jv * 2) = make_float2(vnr, vni);
  }
}

// ---------------- Phase 2: sequential carry scan (1 chain per wave, 64-lane matvec) ----------
constexpr int kD2 = 4;
template <int G>
__global__ __launch_bounds__(64, 1) void pscan_phase2(
    const float* __restrict__ Pg, const float* __restrict__ Vg, float* __restrict__ Sg) {
  const int lane = threadIdx.x;
  const int kq = lane >> 4, i = lane & 15;
  const int chain = blockIdx.x;

  const float* pB = Pg + (size_t)chain * G * 512 + (size_t)i * 32 + 8 * kq;
  const float* vB = Vg + (size_t)chain * G * 32 + 2 * i;
  float* sB = Sg + (size_t)chain * G * 32 + 2 * i;

  float4 bP0[kD2], bP1[kD2]; float2 bV[kD2];
#pragma unroll
  for (int d = 0; d < kD2; ++d) {
    bP0[d] = *(const float4*)(pB + (size_t)d * 512);
    bP1[d] = *(const float4*)(pB + (size_t)d * 512 + 4);
    bV[d] = *(const float2*)(vB + (size_t)d * 32);
  }

  float ykr[4] = {0, 0, 0, 0}, yki[4] = {0, 0, 0, 0};  // y[4kq+kk]
  float ynr = 0.f, yni = 0.f;                          // own y[i]

  for (int gg = 0; gg < G; gg += kD2) {
#pragma unroll
    for (int d = 0; d < kD2; ++d) {
      if (kq == 0) *(float2*)(sB + (size_t)(gg + d) * 32) = make_float2(ynr, yni);  // S_{g-1}
      const float4 p0 = bP0[d], p1 = bP1[d];
      const float2 vv = bV[d];
      const int gn = gg + d + kD2;
      if (gn < G) {
        bP0[d] = *(const float4*)(pB + (size_t)gn * 512);
        bP1[d] = *(const float4*)(pB + (size_t)gn * 512 + 4);
        bV[d] = *(const float2*)(vB + (size_t)gn * 32);
      }
      float tr = p0.x * ykr[0] - p0.y * yki[0] + p0.z * ykr[1] - p0.w * yki[1]
               + p1.x * ykr[2] - p1.y * yki[2] + p1.z * ykr[3] - p1.w * yki[3];
      float ti = p0.x * yki[0] + p0.y * ykr[0] + p0.z * yki[1] + p0.w * ykr[1]
               + p1.x * yki[2] + p1.y * ykr[2] + p1.z * yki[3] + p1.w * ykr[3];
      tr = redq(tr); ti = redq(ti);
      ynr = tr + vv.x;
      yni = ti + vv.y;
#pragma unroll
      for (int kk = 0; kk < 4; ++kk) {
        const int src = (lane & 48) | (4 * kq + kk);
        ykr[kk] = __shfl(ynr, src);
        yki[kk] = __shfl(yni, src);
      }
    }
  }
}

// ---------------- Phase 3: replay chunks from carries (64-lane matvec, high occupancy) ----------
template <int G>
__global__ __launch_bounds__(256, 4) void pscan_phase3(
    const float* __restrict__ Ar, const float* __restrict__ Ai,
    const float* __restrict__ Xr, const float* __restrict__ Xi,
    const float* __restrict__ Sg, float* __restrict__ out) {
  constexpr int CL = kLtot / G;
  const int lane = threadIdx.x & 63;
  const int wid = threadIdx.x >> 6;
  const int kq = lane >> 4, i = lane & 15;
  const int ck = blockIdx.x * 4 + wid;
  const int chain = ck / G, g = ck % G;
  const int bb = chain >> 5, cc = chain & 31;
  const int t0 = g * CL;

  const size_t aBase = ((size_t)(bb * kLtot + t0) * kC + cc) * 256 + (size_t)i * 16 + 4 * kq;
  const size_t xBase = ((size_t)(bb * kLtot + t0) * kC + cc) * 16 + i;
  const size_t aStep = (size_t)kC * 256, xStep = (size_t)kC * 16;
  float* outB = out + ((size_t)(bb * kLtot + t0) * kC + cc) * 32 + 2 * i;

  float ynr, yni, ykr[4], yki[4];
  {
    const float2 s = *(const float2*)(Sg + (size_t)ck * 32 + 2 * i);
    ynr = s.x; yni = s.y;
  }
#pragma unroll
  for (int kk = 0; kk < 4; ++kk) {
    const int src = (lane & 48) | (4 * kq + kk);
    ykr[kk] = __shfl(ynr, src);
    yki[kk] = __shfl(yni, src);
  }

  float4 aR[2], aI[2]; float2 xx[2];
  auto loadT = [&](int t, int s) {
    aR[s] = *(const float4*)(Ar + aBase + (size_t)t * aStep);
    aI[s] = *(const float4*)(Ai + aBase + (size_t)t * aStep);
    xx[s].x = Xr[xBase + (size_t)t * xStep];
    xx[s].y = Xi[xBase + (size_t)t * xStep];
  };
  loadT(0, 0);
  loadT(1, 1);

  for (int t = 0; t < CL; ++t) {
    const int s = t & 1;
    const float4 a4 = aR[s], b4 = aI[s];
    const float2 xv = xx[s];
    float tr = a4.x * ykr[0] - b4.x * yki[0] + a4.y * ykr[1] - b4.y * yki[1]
             + a4.z * ykr[2] - b4.z * yki[2] + a4.w * ykr[3] - b4.w * yki[3];
    float ti = a4.x * yki[0] + b4.x * ykr[0] + a4.y * yki[1] + b4.y * ykr[1]
             + a4.z * yki[2] + b4.z * ykr[2] + a4.w * yki[3] + b4.w * ykr[3];
    tr = redq(tr); ti = redq(ti);
    ynr = tr + xv.x;
    yni = ti + xv.y;
    if (kq == 0) *(float2*)(outB + (size_t)t * (kC * 32)) = make_float2(ynr, yni);
    const int tn = t + 2;
    if (tn < CL) loadT(tn, s);
#pragma unroll
    for (int kk = 0; kk < 4; ++kk) {
      const int src = (lane & 48) | (4 * kq + kk);
      ykr[kk] = __shfl(ynr, src);
      yki[kk] = __shfl(yni, src);
    }
  }
}

template <int G>
static void run_pscan(const float* Ar, const float* Ai, const float* Xr, const float* Xi,
                      float* out, void* d_ws, hipStream_t stream) {
  constexpr int NCK = kNCH * G;
  float* Pg = (float*)d_ws;
  float* Vg = Pg + (size_t)NCK * 512;
  float* Sg = Vg + (size_t)NCK * 32;
  pscan_phase1<G><<<NCK / 4, 256, 0, stream>>>(Ar, Ai, Xr, Xi, Pg, Vg);
  pscan_phase2<G><<<kNCH, 64, 0, stream>>>(Pg, Vg, Sg);
  pscan_phase3<G><<<NCK / 4, 256, 0, stream>>>(Ar, Ai, Xr, Xi, Sg, out);
}

extern "C" void kernel_launch(void* const* d_in, const int* in_sizes, int n_in,
                              void* d_out, int out_size, void* d_ws, size_t ws_size,
                              hipStream_t stream) {
  const float* Ar = (const float*)d_in[0];
  const float* Ai = (const float*)d_in[1];
  const float* Xr = (const float*)d_in[2];
  const float* Xi = (const float*)d_in[3];
  // G=128 needs 128chunks*64chains*(512+32+32)*4B = 18MB of workspace; gate on ws_size.
  if (ws_size >= (size_t)(kNCH * 128) * (512 + 32 + 32) * 4) {
    run_pscan<128>(Ar, Ai, Xr, Xi, (float*)d_out, d_ws, stream);
  } else {
    run_pscan<64>(Ar, Ai, Xr, Xi, (float*)d_out, d_ws, stream);
  }
}

// Round 9
// 78.114 us; speedup vs baseline: 1.5861x; 1.5861x over previous
//
#include <hip/hip_runtime.h>

#define DEVFN static __device__ __forceinline__

constexpr int kLtot = 1024, kC = 32, kB = 2;
constexpr int kG = 64;                 // chunks per chain
constexpr int kCL = kLtot / kG;        // 16 steps per chunk
constexpr int kNCH = kB * kC;          // 64 chains
constexpr int kNCK = kNCH * kG;        // 4096 chunks

// phase1 per-wave LDS: two 2048B A-slots (gload_lds ring) + 144B v-exchange buf
constexpr int kSlotB = 2048;
constexpr int kPbufB = 144;
constexpr int kWaveB = 2 * kSlotB + kPbufB;  // 4240

typedef int v2i __attribute__((ext_vector_type(2)));
typedef __attribute__((ext_vector_type(4))) float f32x4;
typedef __attribute__((ext_vector_type(8))) short s16x8;

union BFrag { unsigned u[4]; s16x8 v; };

DEVFN void gload16(const void* g, void* l) {
  __builtin_amdgcn_global_load_lds((const __attribute__((address_space(1))) void*)g,
                                   (__attribute__((address_space(3))) void*)l, 16, 0, 0);
}

// xor-16 via ds_swizzle (DS pipe), xor-32 via permlane32_swap (R3/R6-proven combo)
DEVFN float redpair16(float x) {
  return x + __int_as_float(__builtin_amdgcn_ds_swizzle(__float_as_int(x), 0x401F));
}
DEVFN float redpair32(float x) {
#if __has_builtin(__builtin_amdgcn_permlane32_swap)
  v2i r = __builtin_amdgcn_permlane32_swap(__float_as_int(x), __float_as_int(x), false, false);
  return __int_as_float(r.x) + __int_as_float(r.y);
#else
  return x + __shfl_xor(x, 32);
#endif
}
DEVFN float redq(float x) { return redpair32(redpair16(x)); }

// split two f32 into packed bf16 hi + packed bf16 lo (residual), RNE via v_cvt_pk_bf16_f32
DEVFN void splitpk(float x0, float x1, unsigned& h, unsigned& l) {
  unsigned hh, ll;
  asm("v_cvt_pk_bf16_f32 %0, %1, %2" : "=v"(hh) : "v"(x0), "v"(x1));
  const float b0 = __uint_as_float(hh << 16);
  const float b1 = __uint_as_float(hh & 0xffff0000u);
  const float s0 = x0 - b0, s1 = x1 - b1;
  asm("v_cvt_pk_bf16_f32 %0, %1, %2" : "=v"(ll) : "v"(s0), "v"(s1));
  h = hh; l = ll;
}

DEVFN f32x4 mfma16(const unsigned a[4], const unsigned b[4], f32x4 c) {
  BFrag A, B;
  A.u[0] = a[0]; A.u[1] = a[1]; A.u[2] = a[2]; A.u[3] = a[3];
  B.u[0] = b[0]; B.u[1] = b[1]; B.u[2] = b[2]; B.u[3] = b[3];
  return __builtin_amdgcn_mfma_f32_16x16x32_bf16(A.v, B.v, c, 0, 0, 0);
}

// assemble word w of the four B-fragments from (Pr[2w],Pr[2w+1],Pi[2w],Pi[2w+1]) of this
// lane's k-slice.  B1 = [Pr; -Pi] (k<16 lanes q<2 take Pr; q>=2 take -Pi), B2 = [Pi; Pr].
#define PUTW(w, r0_, r1_, i0_, i1_)                                \
  do {                                                             \
    unsigned rh_, rl_, ih_, il_;                                   \
    splitpk((r0_), (r1_), rh_, rl_);                               \
    splitpk((i0_), (i1_), ih_, il_);                               \
    b1h[w] = loQ ? rh_ : (ih_ ^ 0x80008000u);                      \
    b1l[w] = loQ ? rl_ : (il_ ^ 0x80008000u);                      \
    b2h[w] = loQ ? ih_ : rh_;                                      \
    b2l[w] = loQ ? il_ : rl_;                                      \
  } while (0)

// ---------------- Phase 1: chunk transition P_g + response v_g (MFMA engine) ----------------
// 1 chunk per wave, 4 waves/block. P-product via mfma_f32_16x16x32_bf16 with complex K-packing
// ([Ar|Ai] x [Pr;-Pi] and [Pi;Pr]) and 2-term bf16 hi/lo split (3 MFMA per accumulator).
// C-layout (col=lane&15, row=(lane>>4)*4+reg) repacked to next step's B-frags with 16 shfl.
// v_g tracked by the proven fp32 VALU side-path. A staged by the proven gload_lds ring.
__global__ __launch_bounds__(256, 4) void pscan_phase1(
    const float* __restrict__ Ar, const float* __restrict__ Ai,
    const float* __restrict__ Xr, const float* __restrict__ Xi,
    float* __restrict__ Pg, float* __restrict__ Vg) {
  __shared__ __align__(16) float ldsF[4 * (kWaveB / 4)];
  const int lane = threadIdx.x & 63;
  const int wid = threadIdx.x >> 6;
  const int q = lane >> 4, j = lane & 15, h = q & 1;
  const bool loQ = (q < 2);
  // v-path lane roles (independent of MFMA roles)
  const int kq = q, ka = (lane >> 2) & 3, kc = lane & 3;
  const int jv = 4 * kc + ka;

  const int ck = blockIdx.x * 4 + wid;
  const int chain = ck >> 6, g = ck & 63;
  const int bb = chain >> 5, cc = chain & 31;
  const int t0 = g * kCL;

  char* ldsW = (char*)ldsF + wid * kWaveB;
  char* pbase = ldsW + 2 * kSlotB;
  const int aOff = (q >> 1) * 1024 + j * 64 + h * 32;     // MFMA A-frag: row j, 8 cols, plane q>>1
  const int laneAv = ka * 64 + kq * 16 + kc * 256;        // v-path: A[jv][4kq..], plane-relative

  const size_t aBase = ((size_t)(bb * kLtot + t0) * kC + cc) * 256;
  const size_t xBase2 = ((size_t)(bb * kLtot + t0) * kC + cc) * 16;
  const float* arPtr = Ar + aBase + (size_t)lane * 4;
  const float* aiPtr = Ai + aBase + (size_t)lane * 4;
  const float* xrPtr = Xr + xBase2 + jv;
  const float* xiPtr = Xi + xBase2 + jv;

  char* vwA = pbase + jv * 8;                             // v write (kq==0 lanes only)
  const char* vrA = pbase + kq * 32;                      // v read slice

  float xrP[2], xiP[2];
  auto issueStep = [&](int t) {                           // exactly 4 vmem ops, always
    const size_t ao = (size_t)t * (kC * 256);
    char* sd = ldsW + (t & 1) * kSlotB;
    gload16(arPtr + ao, sd);
    gload16(aiPtr + ao, sd + 1024);
    xrP[t & 1] = xrPtr[(size_t)t * (kC * 16)];
    xiP[t & 1] = xiPtr[(size_t)t * (kC * 16)];
  };

  issueStep(0);
  asm volatile("" ::: "memory");
  issueStep(1);
  asm volatile("" ::: "memory");

  unsigned b1h[4], b1l[4], b2h[4], b2l[4];   // B-fragments of current P (hi/lo, B1/B2)
  f32x4 accR, accI;                          // P in MFMA C-layout after each step
  float vre[4], vim[4], vnr = 0.f, vni = 0.f;

  // ---- init: P = A_0 (column reads -> B-frags), v = x_0 ----
  asm volatile("s_waitcnt vmcnt(4)" ::: "memory");  // slot 0 resident
  {
    const char* s0 = ldsW;
    float R[8], I[8];
#pragma unroll
    for (int e = 0; e < 8; ++e) {
      R[e] = *(const float*)(s0 + (8 * h + e) * 64 + j * 4);
      I[e] = *(const float*)(s0 + 1024 + (8 * h + e) * 64 + j * 4);
    }
    PUTW(0, R[0], R[1], I[0], I[1]);
    PUTW(1, R[2], R[3], I[2], I[3]);
    PUTW(2, R[4], R[5], I[4], I[5]);
    PUTW(3, R[6], R[7], I[6], I[7]);
    const float* xr0 = Xr + xBase2;
    const float* xi0 = Xi + xBase2;
#pragma unroll
    for (int kk = 0; kk < 4; ++kk) {
      vre[kk] = xr0[4 * kq + kk];
      vim[kk] = xi0[4 * kq + kk];
    }
  }
  asm volatile("s_waitcnt lgkmcnt(0)" ::: "memory");  // slot-0 reads done before re-staging
  issueStep(2);
  asm volatile("" ::: "memory");

  auto stepCompute = [&](int t) {
    const char* sb = ldsW + (t & 1) * kSlotB;
    // A-fragment: 8 consecutive f32 of row j (plane/col-half by q), split hi/lo
    const float4 a0 = *(const float4*)(sb + aOff);
    const float4 a1 = *(const float4*)(sb + aOff + 16);
    unsigned Ah[4], Al[4];
    splitpk(a0.x, a0.y, Ah[0], Al[0]);
    splitpk(a0.z, a0.w, Ah[1], Al[1]);
    splitpk(a1.x, a1.y, Ah[2], Al[2]);
    splitpk(a1.z, a1.w, Ah[3], Al[3]);
    const f32x4 zz = {0.f, 0.f, 0.f, 0.f};
    accR = mfma16(Al, b1h, zz);
    accI = mfma16(Al, b2h, zz);
    accR = mfma16(Ah, b1l, accR);
    accI = mfma16(Ah, b2l, accI);
    accR = mfma16(Ah, b1h, accR);
    accI = mfma16(Ah, b2h, accI);
    // ---- v side-path (fp32 VALU, proven): row jv, own k-slice, redq, exchange ----
    {
      const float4 a4 = *(const float4*)(sb + laneAv);
      const float4 b4 = *(const float4*)(sb + laneAv + 1024);
      float pr = a4.x * vre[0] - b4.x * vim[0];
      float pi = a4.x * vim[0] + b4.x * vre[0];
      pr += a4.y * vre[1] - b4.y * vim[1];  pi += a4.y * vim[1] + b4.y * vre[1];
      pr += a4.z * vre[2] - b4.z * vim[2];  pi += a4.z * vim[2] + b4.z * vre[2];
      pr += a4.w * vre[3] - b4.w * vim[3];  pi += a4.w * vim[3] + b4.w * vre[3];
      pr = redq(pr); pi = redq(pi);
      vnr = pr + xrP[t & 1];
      vni = pi + xiP[t & 1];
      if (kq == 0) *(float2*)vwA = make_float2(vnr, vni);
      const float4 v0 = *(const float4*)(vrA);
      const float4 v1 = *(const float4*)(vrA + 16);
      vre[0] = v0.x; vim[0] = v0.y; vre[1] = v0.z; vim[1] = v0.w;
      vre[2] = v1.x; vim[2] = v1.y; vre[3] = v1.z; vim[3] = v1.w;
    }
  };

  auto repack = [&]() {
    // lane (q,j) needs rows 8h..8h+7 of col j: rows 4(2h)..+3 from lane (2h,j), rows
    // 4(2h+1)..+3 from lane (2h+1,j). C-layout: lane holds rows 4q..4q+3 of col j.
    const int srcA = j | ((2 * h) << 4);
    const int srcB = srcA + 16;
    PUTW(0, __shfl(accR[0], srcA), __shfl(accR[1], srcA), __shfl(accI[0], srcA), __shfl(accI[1], srcA));
    PUTW(1, __shfl(accR[2], srcA), __shfl(accR[3], srcA), __shfl(accI[2], srcA), __shfl(accI[3], srcA));
    PUTW(2, __shfl(accR[0], srcB), __shfl(accR[1], srcB), __shfl(accI[0], srcB), __shfl(accI[1], srcB));
    PUTW(3, __shfl(accR[2], srcB), __shfl(accR[3], srcB), __shfl(accI[2], srcB), __shfl(accI[3], srcB));
  };

#pragma unroll 2
  for (int t = 1; t < kCL - 2; ++t) {
    asm volatile("s_waitcnt vmcnt(4)" ::: "memory");
    stepCompute(t);
    repack();
    issueStep(t + 2);
  }
  asm volatile("s_waitcnt vmcnt(4)" ::: "memory");
  stepCompute(kCL - 2);
  repack();
  asm volatile("s_waitcnt vmcnt(0)" ::: "memory");
  stepCompute(kCL - 1);

  // ---- store P_g (row-major [row][col] float2) from C-layout, and v_g ----
  {
    float* pd = Pg + (size_t)ck * 512;
#pragma unroll
    for (int r = 0; r < 4; ++r) {
      *(float2*)(pd + (4 * q + r) * 32 + j * 2) = make_float2(accR[r], accI[r]);
    }
  }
  if (kq == 0) *(float2*)(Vg + (size_t)ck * 32 + jv * 2) = make_float2(vnr, vni);
}

// ---------------- Phase 2: sequential carry scan (1 chain per wave, 64-lane matvec) ----------
constexpr int kD2 = 4;
__global__ __launch_bounds__(64, 1) void pscan_phase2(
    const float* __restrict__ Pg, const float* __restrict__ Vg, float* __restrict__ Sg) {
  const int lane = threadIdx.x;
  const int kq = lane >> 4, i = lane & 15;
  const int chain = blockIdx.x;

  const float* pB = Pg + (size_t)chain * kG * 512 + (size_t)i * 32 + 8 * kq;
  const float* vB = Vg + (size_t)chain * kG * 32 + 2 * i;
  float* sB = Sg + (size_t)chain * kG * 32 + 2 * i;

  float4 bP0[kD2], bP1[kD2]; float2 bV[kD2];
#pragma unroll
  for (int d = 0; d < kD2; ++d) {
    bP0[d] = *(const float4*)(pB + (size_t)d * 512);
    bP1[d] = *(const float4*)(pB + (size_t)d * 512 + 4);
    bV[d] = *(const float2*)(vB + (size_t)d * 32);
  }

  float ykr[4] = {0, 0, 0, 0}, yki[4] = {0, 0, 0, 0};
  float ynr = 0.f, yni = 0.f;

  for (int gg = 0; gg < kG; gg += kD2) {
#pragma unroll
    for (int d = 0; d < kD2; ++d) {
      if (kq == 0) *(float2*)(sB + (size_t)(gg + d) * 32) = make_float2(ynr, yni);  // S_{g-1}
      const float4 p0 = bP0[d], p1 = bP1[d];
      const float2 vv = bV[d];
      const int gn = gg + d + kD2;
      if (gn < kG) {
        bP0[d] = *(const float4*)(pB + (size_t)gn * 512);
        bP1[d] = *(const float4*)(pB + (size_t)gn * 512 + 4);
        bV[d] = *(const float2*)(vB + (size_t)gn * 32);
      }
      float tr = p0.x * ykr[0] - p0.y * yki[0] + p0.z * ykr[1] - p0.w * yki[1]
               + p1.x * ykr[2] - p1.y * yki[2] + p1.z * ykr[3] - p1.w * yki[3];
      float ti = p0.x * yki[0] + p0.y * ykr[0] + p0.z * yki[1] + p0.w * ykr[1]
               + p1.x * yki[2] + p1.y * ykr[2] + p1.z * yki[3] + p1.w * ykr[3];
      tr = redq(tr); ti = redq(ti);
      ynr = tr + vv.x;
      yni = ti + vv.y;
#pragma unroll
      for (int kk = 0; kk < 4; ++kk) {
        const int src = (lane & 48) | (4 * kq + kk);
        ykr[kk] = __shfl(ynr, src);
        yki[kk] = __shfl(yni, src);
      }
    }
  }
}

// ---------------- Phase 3: replay chunks from carries (64-lane matvec, high occupancy) ----------
__global__ __launch_bounds__(256, 4) void pscan_phase3(
    const float* __restrict__ Ar, const float* __restrict__ Ai,
    const float* __restrict__ Xr, const float* __restrict__ Xi,
    const float* __restrict__ Sg, float* __restrict__ out) {
  const int lane = threadIdx.x & 63;
  const int wid = threadIdx.x >> 6;
  const int kq = lane >> 4, i = lane & 15;
  const int ck = blockIdx.x * 4 + wid;
  const int chain = ck >> 6, g = ck & 63;
  const int bb = chain >> 5, cc = chain & 31;
  const int t0 = g * kCL;

  const size_t aBase = ((size_t)(bb * kLtot + t0) * kC + cc) * 256 + (size_t)i * 16 + 4 * kq;
  const size_t xBase = ((size_t)(bb * kLtot + t0) * kC + cc) * 16 + i;
  const size_t aStep = (size_t)kC * 256, xStep = (size_t)kC * 16;
  float* outB = out + ((size_t)(bb * kLtot + t0) * kC + cc) * 32 + 2 * i;

  float ynr, yni, ykr[4], yki[4];
  {
    const float2 s = *(const float2*)(Sg + (size_t)ck * 32 + 2 * i);
    ynr = s.x; yni = s.y;
  }
#pragma unroll
  for (int kk = 0; kk < 4; ++kk) {
    const int src = (lane & 48) | (4 * kq + kk);
    ykr[kk] = __shfl(ynr, src);
    yki[kk] = __shfl(yni, src);
  }

  float4 aR[2], aI[2]; float2 xx[2];
  auto loadT = [&](int t, int s) {
    aR[s] = *(const float4*)(Ar + aBase + (size_t)t * aStep);
    aI[s] = *(const float4*)(Ai + aBase + (size_t)t * aStep);
    xx[s].x = Xr[xBase + (size_t)t * xStep];
    xx[s].y = Xi[xBase + (size_t)t * xStep];
  };
  loadT(0, 0);
  loadT(1, 1);

  for (int t = 0; t < kCL; ++t) {
    const int s = t & 1;
    const float4 a4 = aR[s], b4 = aI[s];
    const float2 xv = xx[s];
    float tr = a4.x * ykr[0] - b4.x * yki[0] + a4.y * ykr[1] - b4.y * yki[1]
             + a4.z * ykr[2] - b4.z * yki[2] + a4.w * ykr[3] - b4.w * yki[3];
    float ti = a4.x * yki[0] + b4.x * ykr[0] + a4.y * yki[1] + b4.y * ykr[1]
             + a4.z * yki[2] + b4.z * ykr[2] + a4.w * yki[3] + b4.w * ykr[3];
    tr = redq(tr); ti = redq(ti);
    ynr = tr + xv.x;
    yni = ti + xv.y;
    if (kq == 0) *(float2*)(outB + (size_t)t * (kC * 32)) = make_float2(ynr, yni);
    const int tn = t + 2;
    if (tn < kCL) loadT(tn, s);
#pragma unroll
    for (int kk = 0; kk < 4; ++kk) {
      const int src = (lane & 48) | (4 * kq + kk);
      ykr[kk] = __shfl(ynr, src);
      yki[kk] = __shfl(yni, src);
    }
  }
}

extern "C" void kernel_launch(void* const* d_in, const int* in_sizes, int n_in,
                              void* d_out, int out_size, void* d_ws, size_t ws_size,
                              hipStream_t stream) {
  const float* Ar = (const float*)d_in[0];
  const float* Ai = (const float*)d_in[1];
  const float* Xr = (const float*)d_in[2];
  const float* Xi = (const float*)d_in[3];
  // Workspace: Pg 8MB + Vg 512KB + Sg 512KB = 9MB
  float* Pg = (float*)d_ws;
  float* Vg = Pg + (size_t)kNCK * 512;
  float* Sg = Vg + (size_t)kNCK * 32;

  pscan_phase1<<<kNCK / 4, 256, 0, stream>>>(Ar, Ai, Xr, Xi, Pg, Vg);
  pscan_phase2<<<kNCH, 64, 0, stream>>>(Pg, Vg, Sg);
  pscan_phase3<<<kNCK / 4, 256, 0, stream>>>(Ar, Ai, Xr, Xi, Sg, (float*)d_out);
}